// Round 3
// baseline (305.528 us; speedup 1.0000x reference)
//
#include <hip/hip_runtime.h>
#include <math.h>

// Problem constants
#define Bn 16
#define Qn 64
#define Nn 16384
#define Dn 128
#define NT 128                  // n-tile per k_logits block
#define NTILES (Nn / NT)        // 128
#define NCHUNK 256              // n per k_pv block -> grid 1024 = 4 blocks/CU
#define NCHUNKS (Nn / NCHUNK)   // 64
#define SLAB 64                 // n per k_pv inner phase (2 barriers per SLAB)

#define RES_ELEMS  (Bn * Qn * Dn)      // 131072
#define SOFT_OFF   (RES_ELEMS)
#define LOG_OFF    (RES_ELEMS + Bn * Qn * Nn)

#define NEGF (-3.4e38f)

typedef __attribute__((ext_vector_type(8))) short short8;   // 8 bf16 (4 VGPRs)
typedef float f32x4 __attribute__((ext_vector_type(4)));    // MFMA accumulator

typedef union { unsigned int u[4]; short8 v; } pk8;

// HW packed f32->bf16 (RTNE): dst.lo16 = bf16(a), dst.hi16 = bf16(b)
__device__ __forceinline__ unsigned int cvt_pk_bf16(float a, float b) {
    unsigned int r;
    asm("v_cvt_pk_bf16_f32 %0, %1, %2" : "=v"(r) : "v"(a), "v"(b));
    return r;
}

// Swizzled u16 index in a [rows][64]-u16 plane: XOR col bits 3..5 with row bits 0..2.
// Keeps 8B writes and 16B reads aligned; bank-balanced both ways. (Verified R1/R2.)
__device__ __forceinline__ int swz(int row, int col) {
    return row * 64 + (col ^ ((row & 7) << 3));
}

// ---------------------------------------------------------------------------
// K1: logits = Q @ A^T via split-bf16 MFMA (hi*hi + hi*lo + lo*hi == fp32-ish)
// Block: 256 thr = 4 waves. Tile M=64 q x N=128 n, K=128 in 2 chunks of 64.
// LDS 48 KB (pitch-64 + XOR swizzle) -> 3 blocks/CU. cvt_pk staging (R2).
// Epilogue: acc -> LDS (fp32) -> coalesced float4 logits stores + masked stats.
// [Unchanged from R2 -- held fixed to isolate k_pv changes this round.]
// ---------------------------------------------------------------------------
__global__ __launch_bounds__(256, 3) void k_logits(
    const float* __restrict__ qv, const float* __restrict__ A,
    const int* __restrict__ nodeNum,
    float* __restrict__ logits,
    float* __restrict__ pmax, float* __restrict__ psum)
{
    const int b = blockIdx.y, tile = blockIdx.x;
    const int n0 = tile * NT;
    const int tid = threadIdx.x;
    const int lane = tid & 63, wave = tid >> 6;
    const int qd = lane >> 4, cc = lane & 15;   // quad, col-in-16

    // staging (phase 1): QHI/QLO 64x64 u16, AHI/ALO 128x64 u16 = 49152 B (swizzled)
    // alias (phase 2): CB 64x132 f32 (33792 B), REDM/REDS 64x17 f32
    __shared__ __align__(16) unsigned char smem[49152];
    unsigned short* QHI = (unsigned short*)smem;
    unsigned short* QLO = QHI + 64 * 64;
    unsigned short* AHI = QLO + 64 * 64;
    unsigned short* ALO = AHI + 128 * 64;
    float* CB   = (float*)smem;            // [64][132]
    float* REDM = ((float*)smem) + 64 * 132;
    float* REDS = REDM + 64 * 17;

    f32x4 acc[4][2];
#pragma unroll
    for (int mi = 0; mi < 4; mi++)
#pragma unroll
        for (int ni = 0; ni < 2; ni++) acc[mi][ni] = 0.f;

    const float* qb = qv + (size_t)b * Qn * Dn;
    const float* Ab = A  + (size_t)b * Nn * Dn + (size_t)n0 * Dn;

    const int r16 = tid >> 4, c4 = tid & 15;    // staging row-base / float4 col

    for (int kk = 0; kk < Dn; kk += 64) {
        __syncthreads();
        // stage Q slab 64x64 (4 float4/thread) + A slab 128x64 (8 float4/thread)
#pragma unroll
        for (int t = 0; t < 4; t++) {
            int row = r16 + 16 * t;
            float4 v = *(const float4*)(qb + (size_t)row * Dn + kk + c4 * 4);
            unsigned int h01 = cvt_pk_bf16(v.x, v.y);
            unsigned int h23 = cvt_pk_bf16(v.z, v.w);
            float rx = v.x - __uint_as_float(h01 << 16);
            float ry = v.y - __uint_as_float(h01 & 0xFFFF0000u);
            float rz = v.z - __uint_as_float(h23 << 16);
            float rw = v.w - __uint_as_float(h23 & 0xFFFF0000u);
            unsigned int l01 = cvt_pk_bf16(rx, ry);
            unsigned int l23 = cvt_pk_bf16(rz, rw);
            int idx = swz(row, c4 * 4);
            uint2 hh; hh.x = h01; hh.y = h23;
            uint2 ll; ll.x = l01; ll.y = l23;
            *(uint2*)(QHI + idx) = hh;
            *(uint2*)(QLO + idx) = ll;
        }
#pragma unroll
        for (int t = 0; t < 8; t++) {
            int row = r16 + 16 * t;
            float4 v = *(const float4*)(Ab + (size_t)row * Dn + kk + c4 * 4);
            unsigned int h01 = cvt_pk_bf16(v.x, v.y);
            unsigned int h23 = cvt_pk_bf16(v.z, v.w);
            float rx = v.x - __uint_as_float(h01 << 16);
            float ry = v.y - __uint_as_float(h01 & 0xFFFF0000u);
            float rz = v.z - __uint_as_float(h23 << 16);
            float rw = v.w - __uint_as_float(h23 & 0xFFFF0000u);
            unsigned int l01 = cvt_pk_bf16(rx, ry);
            unsigned int l23 = cvt_pk_bf16(rz, rw);
            int idx = swz(row, c4 * 4);
            uint2 hh; hh.x = h01; hh.y = h23;
            uint2 ll; ll.x = l01; ll.y = l23;
            *(uint2*)(AHI + idx) = hh;
            *(uint2*)(ALO + idx) = ll;
        }
        __syncthreads();
#pragma unroll
        for (int ks = 0; ks < 64; ks += 32) {
            const int ko = ks + qd * 8;   // u16 col of this lane's k-octet
            short8 qh[4], ql[4], ah[2], al[2];
#pragma unroll
            for (int mi = 0; mi < 4; mi++) {
                int r = mi * 16 + cc;
                int idx = swz(r, ko);
                qh[mi] = *(const short8*)(QHI + idx);
                ql[mi] = *(const short8*)(QLO + idx);
            }
#pragma unroll
            for (int ni = 0; ni < 2; ni++) {
                int r = (wave * 2 + ni) * 16 + cc;
                int idx = swz(r, ko);
                ah[ni] = *(const short8*)(AHI + idx);
                al[ni] = *(const short8*)(ALO + idx);
            }
#pragma unroll
            for (int mi = 0; mi < 4; mi++)
#pragma unroll
                for (int ni = 0; ni < 2; ni++) {
                    acc[mi][ni] = __builtin_amdgcn_mfma_f32_16x16x32_bf16(
                        ql[mi], ah[ni], acc[mi][ni], 0, 0, 0);
                    acc[mi][ni] = __builtin_amdgcn_mfma_f32_16x16x32_bf16(
                        qh[mi], al[ni], acc[mi][ni], 0, 0, 0);
                    acc[mi][ni] = __builtin_amdgcn_mfma_f32_16x16x32_bf16(
                        qh[mi], ah[ni], acc[mi][ni], 0, 0, 0);
                }
        }
    }

    __syncthreads();   // staging dead; alias LDS as CB
    // C-layout: col = lane&15 (n), row = quad*4 + reg (q)
#pragma unroll
    for (int mi = 0; mi < 4; mi++)
#pragma unroll
        for (int ni = 0; ni < 2; ni++)
#pragma unroll
            for (int r = 0; r < 4; r++) {
                int q = mi * 16 + qd * 4 + r;
                int n = (wave * 2 + ni) * 16 + cc;
                CB[q * 132 + n] = acc[mi][ni][r];
            }
    __syncthreads();

    const int nv = nodeNum[b];
    // coalesced logits store
#pragma unroll
    for (int t = 0; t < 8; t++) {
        int u = tid + t * 256;
        int q = u >> 5, ng = u & 31;
        float4 v = *(const float4*)(CB + q * 132 + ng * 4);
        *(float4*)(logits + ((size_t)(b * Qn + q)) * Nn + n0 + ng * 4) = v;
    }
    // masked per-tile stats
#pragma unroll
    for (int t = 0; t < 4; t++) {
        int u = tid + t * 256;
        int q = u >> 4, c = u & 15;
        const float* base = CB + q * 132 + c * 8;
        float m = NEGF;
#pragma unroll
        for (int j = 0; j < 8; j++)
            if (n0 + c * 8 + j < nv) m = fmaxf(m, base[j]);
        float s = 0.f;
#pragma unroll
        for (int j = 0; j < 8; j++)
            if (n0 + c * 8 + j < nv) s += __expf(base[j] - m);
        REDM[q * 17 + c] = m;
        REDS[q * 17 + c] = s;
    }
    __syncthreads();
    if (tid < Qn) {
        int q = tid;
        float M = NEGF;
#pragma unroll
        for (int t = 0; t < 16; t++) M = fmaxf(M, REDM[q * 17 + t]);
        float S = 0.f;
#pragma unroll
        for (int t = 0; t < 16; t++)
            S += REDS[q * 17 + t] * __expf(REDM[q * 17 + t] - M);
        pmax[((size_t)(b * Qn + q)) * NTILES + tile] = M;
        psum[((size_t)(b * Qn + q)) * NTILES + tile] = S;
    }
}

// ---------------------------------------------------------------------------
// K2: combine 128 per-tile partials per (b,q) row -> M, 1/L
// ---------------------------------------------------------------------------
__global__ __launch_bounds__(64) void k_rows(
    const float* __restrict__ pmax, const float* __restrict__ psum,
    float* __restrict__ Mrow, float* __restrict__ invL)
{
    const int row = blockIdx.x;
    const int t = threadIdx.x;
    const float* pm = pmax + (size_t)row * NTILES;
    const float* ps = psum + (size_t)row * NTILES;
    float m0 = pm[t], m1 = pm[t + 64];
    float s0 = ps[t], s1 = ps[t + 64];
    float m = fmaxf(m0, m1);
#pragma unroll
    for (int o = 32; o >= 1; o >>= 1) m = fmaxf(m, __shfl_xor(m, o, 64));
    float s = s0 * __expf(m0 - m) + s1 * __expf(m1 - m);
#pragma unroll
    for (int o = 32; o >= 1; o >>= 1) s += __shfl_xor(s, o, 64);
    if (t == 0) { Mrow[row] = m; invL[row] = 1.0f / s; }
}

// ---------------------------------------------------------------------------
// K3: softmax (p -> prob_soft fp32 + bf16 P-tile in LDS) then P @ A via MFMA.
// Grid 1024 = 4 blocks/CU. SLAB=64: 2 barriers per 64-n phase (half the
// barrier count of the 32-n version), double the global-load batch per phase
// (MLP for L3/HBM latency), 16 MFMA/wave/phase under setprio (T5: independent
// blocks at different phases = role diversity present).
// Epilogue: plain stores to partial[chunk] -- NO atomics (R2's 8.4M contended
// atomicAdds were the suspected +15-25us regression); k_red reduces.
// ---------------------------------------------------------------------------
__global__ __launch_bounds__(256, 4) void k_pv(
    const float* __restrict__ A, const int* __restrict__ nodeNum,
    const float* __restrict__ logits,
    const float* __restrict__ Mrow, const float* __restrict__ invL,
    float* __restrict__ soft, float* __restrict__ partial)
{
    const int b = blockIdx.y, chunk = blockIdx.x;
    const int tid = threadIdx.x;
    const int lane = tid & 63, wave = tid >> 6;
    const int qd = lane >> 4, cc = lane & 15;

    __shared__ __align__(16) unsigned short PS[64 * 72];   // P bf16 [q][64n], pitch 72
    __shared__ __align__(16) unsigned int  TMP2[32 * 132]; // A pairs [n2][128d], pitch 132
    __shared__ float MS[64], LS[64];

    if (tid < Qn) {
        MS[tid] = Mrow[b * Qn + tid];
        LS[tid] = invL[b * Qn + tid];
    }

    f32x4 acc[4][2];
#pragma unroll
    for (int mi = 0; mi < 4; mi++)
#pragma unroll
        for (int ni = 0; ni < 2; ni++) acc[mi][ni] = 0.f;

    const int nv = nodeNum[b];
    const float* Abase = A + (size_t)b * Nn * Dn;

    for (int s = 0; s < NCHUNK / SLAB; s++) {
        const int n0 = chunk * NCHUNK + s * SLAB;
        __syncthreads();   // PS/TMP2 reuse fence (and MS/LS on first iter)

        // softmax: 64q x 64n = 1024 float4-units
#pragma unroll
        for (int t = 0; t < 4; t++) {
            int u = tid + t * 256;
            int q = u >> 4, ng = u & 15;
            size_t go = ((size_t)(b * Qn + q)) * Nn + n0 + ng * 4;
            float4 l4 = *(const float4*)(logits + go);
            float mq = MS[q], iq = LS[q];
            int nb = n0 + ng * 4;
            float4 p;
            p.x = (nb + 0 < nv) ? __expf(l4.x - mq) * iq : 0.f;
            p.y = (nb + 1 < nv) ? __expf(l4.y - mq) * iq : 0.f;
            p.z = (nb + 2 < nv) ? __expf(l4.z - mq) * iq : 0.f;
            p.w = (nb + 3 < nv) ? __expf(l4.w - mq) * iq : 0.f;
            *(float4*)(soft + go) = p;
            unsigned int* dst = (unsigned int*)(PS + q * 72 + ng * 4);
            dst[0] = cvt_pk_bf16(p.x, p.y);
            dst[1] = cvt_pk_bf16(p.z, p.w);
        }
        // stage A slab 64n x 128d as (n,n+1) bf16 pairs: 1024 uint4-units
#pragma unroll
        for (int t = 0; t < 4; t++) {
            int u = tid + t * 256;
            int n2 = u >> 5, db = u & 31;
            const float* r0 = Abase + (size_t)(n0 + n2 * 2) * Dn + db * 4;
            float4 a0 = *(const float4*)r0;          // n even
            float4 a1 = *(const float4*)(r0 + Dn);   // n odd
            uint4 w;
            w.x = cvt_pk_bf16(a0.x, a1.x);
            w.y = cvt_pk_bf16(a0.y, a1.y);
            w.z = cvt_pk_bf16(a0.z, a1.z);
            w.w = cvt_pk_bf16(a0.w, a1.w);
            *(uint4*)(TMP2 + n2 * 132 + db * 4) = w;
        }
        __syncthreads();

        __builtin_amdgcn_s_setprio(1);
#pragma unroll
        for (int ks = 0; ks < 2; ks++) {
            short8 pf[4];
#pragma unroll
            for (int mi = 0; mi < 4; mi++)
                pf[mi] = *(const short8*)(PS + (mi * 16 + cc) * 72 + ks * 32 + qd * 8);
#pragma unroll
            for (int ni = 0; ni < 2; ni++) {
                int d = (wave * 2 + ni) * 16 + cc;
                pk8 bfr;
#pragma unroll
                for (int j = 0; j < 4; j++)
                    bfr.u[j] = TMP2[(ks * 16 + qd * 4 + j) * 132 + d];
#pragma unroll
                for (int mi = 0; mi < 4; mi++)
                    acc[mi][ni] = __builtin_amdgcn_mfma_f32_16x16x32_bf16(
                        pf[mi], bfr.v, acc[mi][ni], 0, 0, 0);
            }
        }
        __builtin_amdgcn_s_setprio(0);
    }

    float* pout = partial + (size_t)chunk * RES_ELEMS + (size_t)(b * Qn) * Dn;
#pragma unroll
    for (int mi = 0; mi < 4; mi++)
#pragma unroll
        for (int ni = 0; ni < 2; ni++)
#pragma unroll
            for (int r = 0; r < 4; r++) {
                int q = mi * 16 + qd * 4 + r;
                int d = (wave * 2 + ni) * 16 + cc;
                pout[q * Dn + d] = acc[mi][ni][r];
            }
}

// ---------------------------------------------------------------------------
// K4: res = sum over 64 chunk-partials
// ---------------------------------------------------------------------------
__global__ __launch_bounds__(256) void k_red(
    const float* __restrict__ partial, float* __restrict__ res)
{
    int g = blockIdx.x * 256 + threadIdx.x;
    float s = 0.f;
#pragma unroll
    for (int t = 0; t < NCHUNKS; t++)
        s += partial[(size_t)t * RES_ELEMS + g];
    res[g] = s;
}

extern "C" void kernel_launch(void* const* d_in, const int* in_sizes, int n_in,
                              void* d_out, int out_size, void* d_ws, size_t ws_size,
                              hipStream_t stream) {
    const float* qv = (const float*)d_in[0];
    const float* A  = (const float*)d_in[1];
    const int*   nn = (const int*)d_in[2];

    float* out    = (float*)d_out;
    float* res    = out;
    float* soft   = out + SOFT_OFF;
    float* logits = out + LOG_OFF;

    float* ws      = (float*)d_ws;
    float* pmax    = ws;
    float* psum    = pmax + (size_t)Bn * Qn * NTILES;
    float* Mrow    = psum + (size_t)Bn * Qn * NTILES;
    float* invL    = Mrow + Bn * Qn;
    float* partial = invL + Bn * Qn;

    dim3 blk(256);
    k_logits<<<dim3(NTILES, Bn), blk, 0, stream>>>(qv, A, nn, logits, pmax, psum);
    k_rows<<<Bn * Qn, 64, 0, stream>>>(pmax, psum, Mrow, invL);
    k_pv<<<dim3(NCHUNKS, Bn), blk, 0, stream>>>(A, nn, logits, Mrow, invL, soft, partial);
    k_red<<<RES_ELEMS / 256, blk, 0, stream>>>(partial, res);
}

// Round 6
// 296.314 us; speedup vs baseline: 1.0311x; 1.0311x over previous
//
#include <hip/hip_runtime.h>
#include <math.h>

// Problem constants
#define Bn 16
#define Qn 64
#define Nn 16384
#define Dn 128
#define NT 128                  // n-tile per k_logits block
#define NTILES (Nn / NT)        // 128
#define NCHUNK 256              // n per k_pv block -> grid 1024 = 4 blocks/CU
#define NCHUNKS (Nn / NCHUNK)   // 64
#define NCOPY 8                 // atomic-spreading copies of res

#define RES_ELEMS  (Bn * Qn * Dn)      // 131072
#define SOFT_OFF   (RES_ELEMS)
#define LOG_OFF    (RES_ELEMS + Bn * Qn * Nn)

#define NEGF (-3.4e38f)

typedef __attribute__((ext_vector_type(8))) short short8;       // 8 bf16
typedef __attribute__((ext_vector_type(8))) _Float16 half8;     // 8 fp16 (4 VGPRs)
typedef __attribute__((ext_vector_type(2))) __fp16 fp16x2;      // cvt_pkrtz result type
typedef float f32x4 __attribute__((ext_vector_type(4)));        // MFMA accumulator

typedef union { unsigned int u[4]; short8 v; } pk8;
typedef union { fp16x2 h2[2]; ushort4 s; } h4pack;

// HW packed f32->bf16 (RTNE): dst.lo16 = bf16(a), dst.hi16 = bf16(b)
__device__ __forceinline__ unsigned int cvt_pk_bf16(float a, float b) {
    unsigned int r;
    asm("v_cvt_pk_bf16_f32 %0, %1, %2" : "=v"(r) : "v"(a), "v"(b));
    return r;
}

// Swizzled u16 index in a [rows][128]-u16 plane: XOR col bits 3..5 with row
// bits 0..2. Row pitch 128 u16 = 32 banks, so banks are row-invariant without
// swizzle; XOR spreads 8 consecutive rows across 8 bank-groups (2-way = free).
// 8B writes and 16B reads stay aligned (XOR only touches bits >= 3).
__device__ __forceinline__ int swz128(int row, int col) {
    return row * 128 + (col ^ ((row & 7) << 3));
}

// ---------------------------------------------------------------------------
// K0: zero the 8 res copies (atomic accumulation targets for k_pv)
// ---------------------------------------------------------------------------
__global__ __launch_bounds__(256) void k_zero(float* __restrict__ partial8)
{
    int g = blockIdx.x * 256 + threadIdx.x;
    float4 z; z.x = 0.f; z.y = 0.f; z.z = 0.f; z.w = 0.f;
    ((float4*)partial8)[g] = z;
}

// ---------------------------------------------------------------------------
// K1: logits = Q @ A^T via SINGLE-pass fp16 MFMA (error sigma ~0.02, max
// ~0.11 over 16.8M logits -- well under 0.25 tolerance; replaces the 3-term
// split-bf16 which cost 3x MFMA + ~12 VALU/float4 residual math).
// Full K=128 staged at once: QH 64x128 + AH 128x128 u16 = 48 KB, 3 blocks/CU,
// only 2 barriers in the main pass (was 4).
// Epilogue: acc -> LDS (fp32) -> coalesced float4 logits stores + masked stats.
// ---------------------------------------------------------------------------
__global__ __launch_bounds__(256, 3) void k_logits(
    const float* __restrict__ qv, const float* __restrict__ A,
    const int* __restrict__ nodeNum,
    float* __restrict__ logits,
    float* __restrict__ pmax, float* __restrict__ psum)
{
    const int b = blockIdx.y, tile = blockIdx.x;
    const int n0 = tile * NT;
    const int tid = threadIdx.x;
    const int lane = tid & 63, wave = tid >> 6;
    const int qd = lane >> 4, cc = lane & 15;   // quad, col-in-16

    // staging (phase 1): QH 64x128 u16 (16 KB) + AH 128x128 u16 (32 KB)
    // alias (phase 2): CB 64x132 f32 (33792 B), REDM/REDS 64x17 f32 (8704 B)
    __shared__ __align__(16) unsigned char smem[49152];
    unsigned short* QH = (unsigned short*)smem;
    unsigned short* AH = QH + 64 * 128;
    float* CB   = (float*)smem;            // [64][132]
    float* REDM = ((float*)smem) + 64 * 132;
    float* REDS = REDM + 64 * 17;

    f32x4 acc[4][2];
#pragma unroll
    for (int mi = 0; mi < 4; mi++)
#pragma unroll
        for (int ni = 0; ni < 2; ni++) acc[mi][ni] = 0.f;

    const float* qb = qv + (size_t)b * Qn * Dn;
    const float* Ab = A  + (size_t)b * Nn * Dn + (size_t)n0 * Dn;

    // stage Q 64x128: 2048 float4-units (8/thread); A 128x128: 4096 (16/thread)
#pragma unroll
    for (int t = 0; t < 8; t++) {
        int u = tid + t * 256;
        int row = u >> 5, c8 = u & 31;
        float4 v = *(const float4*)(qb + (size_t)row * Dn + c8 * 4);
        h4pack p;
        p.h2[0] = __builtin_amdgcn_cvt_pkrtz(v.x, v.y);
        p.h2[1] = __builtin_amdgcn_cvt_pkrtz(v.z, v.w);
        *(ushort4*)(QH + swz128(row, c8 * 4)) = p.s;
    }
#pragma unroll
    for (int t = 0; t < 16; t++) {
        int u = tid + t * 256;
        int row = u >> 5, c8 = u & 31;
        float4 v = *(const float4*)(Ab + (size_t)row * Dn + c8 * 4);
        h4pack p;
        p.h2[0] = __builtin_amdgcn_cvt_pkrtz(v.x, v.y);
        p.h2[1] = __builtin_amdgcn_cvt_pkrtz(v.z, v.w);
        *(ushort4*)(AH + swz128(row, c8 * 4)) = p.s;
    }
    __syncthreads();

#pragma unroll
    for (int ks = 0; ks < 128; ks += 32) {
        const int ko = ks + qd * 8;   // u16 col of this lane's k-octet
        half8 qh[4], ah[2];
#pragma unroll
        for (int mi = 0; mi < 4; mi++)
            qh[mi] = *(const half8*)(QH + swz128(mi * 16 + cc, ko));
#pragma unroll
        for (int ni = 0; ni < 2; ni++)
            ah[ni] = *(const half8*)(AH + swz128((wave * 2 + ni) * 16 + cc, ko));
#pragma unroll
        for (int mi = 0; mi < 4; mi++)
#pragma unroll
            for (int ni = 0; ni < 2; ni++)
                acc[mi][ni] = __builtin_amdgcn_mfma_f32_16x16x32_f16(
                    qh[mi], ah[ni], acc[mi][ni], 0, 0, 0);
    }

    __syncthreads();   // staging dead; alias LDS as CB
    // C-layout: col = lane&15 (n), row = quad*4 + reg (q)
#pragma unroll
    for (int mi = 0; mi < 4; mi++)
#pragma unroll
        for (int ni = 0; ni < 2; ni++)
#pragma unroll
            for (int r = 0; r < 4; r++) {
                int q = mi * 16 + qd * 4 + r;
                int n = (wave * 2 + ni) * 16 + cc;
                CB[q * 132 + n] = acc[mi][ni][r];
            }
    __syncthreads();

    const int nv = nodeNum[b];
    // coalesced logits store
#pragma unroll
    for (int t = 0; t < 8; t++) {
        int u = tid + t * 256;
        int q = u >> 5, ng = u & 31;
        float4 v = *(const float4*)(CB + q * 132 + ng * 4);
        *(float4*)(logits + ((size_t)(b * Qn + q)) * Nn + n0 + ng * 4) = v;
    }
    // masked per-tile stats
#pragma unroll
    for (int t = 0; t < 4; t++) {
        int u = tid + t * 256;
        int q = u >> 4, c = u & 15;
        const float* base = CB + q * 132 + c * 8;
        float m = NEGF;
#pragma unroll
        for (int j = 0; j < 8; j++)
            if (n0 + c * 8 + j < nv) m = fmaxf(m, base[j]);
        float s = 0.f;
#pragma unroll
        for (int j = 0; j < 8; j++)
            if (n0 + c * 8 + j < nv) s += __expf(base[j] - m);
        REDM[q * 17 + c] = m;
        REDS[q * 17 + c] = s;
    }
    __syncthreads();
    if (tid < Qn) {
        int q = tid;
        float M = NEGF;
#pragma unroll
        for (int t = 0; t < 16; t++) M = fmaxf(M, REDM[q * 17 + t]);
        float S = 0.f;
#pragma unroll
        for (int t = 0; t < 16; t++)
            S += REDS[q * 17 + t] * __expf(REDM[q * 17 + t] - M);
        pmax[((size_t)(b * Qn + q)) * NTILES + tile] = M;
        psum[((size_t)(b * Qn + q)) * NTILES + tile] = S;
    }
}

// ---------------------------------------------------------------------------
// K2: combine 128 per-tile partials per (b,q) row -> M, 1/L
// ---------------------------------------------------------------------------
__global__ __launch_bounds__(64) void k_rows(
    const float* __restrict__ pmax, const float* __restrict__ psum,
    float* __restrict__ Mrow, float* __restrict__ invL)
{
    const int row = blockIdx.x;
    const int t = threadIdx.x;
    const float* pm = pmax + (size_t)row * NTILES;
    const float* ps = psum + (size_t)row * NTILES;
    float m0 = pm[t], m1 = pm[t + 64];
    float s0 = ps[t], s1 = ps[t + 64];
    float m = fmaxf(m0, m1);
#pragma unroll
    for (int o = 32; o >= 1; o >>= 1) m = fmaxf(m, __shfl_xor(m, o, 64));
    float s = s0 * __expf(m0 - m) + s1 * __expf(m1 - m);
#pragma unroll
    for (int o = 32; o >= 1; o >>= 1) s += __shfl_xor(s, o, 64);
    if (t == 0) { Mrow[row] = m; invL[row] = 1.0f / s; }
}

// ---------------------------------------------------------------------------
// K3: softmax (p -> prob_soft fp32 + bf16 P-tile in LDS) then P @ A via MFMA.
// Exact R2 body (SLAB=32, the 290us-best config) except the epilogue target:
// atomicAdd into partial8[chunk & 7] -- spreads per-address contention 64 -> 8
// (R3 proved the partial-buffer round-trip costs more than the atomics did).
// ---------------------------------------------------------------------------
__global__ __launch_bounds__(256, 4) void k_pv(
    const float* __restrict__ A, const int* __restrict__ nodeNum,
    const float* __restrict__ logits,
    const float* __restrict__ Mrow, const float* __restrict__ invL,
    float* __restrict__ soft, float* __restrict__ partial8)
{
    const int b = blockIdx.y, chunk = blockIdx.x;
    const int tid = threadIdx.x;
    const int lane = tid & 63, wave = tid >> 6;
    const int qd = lane >> 4, cc = lane & 15;

    __shared__ __align__(16) unsigned short PS[64 * 40];   // P bf16 [q][32n], pitch 40
    __shared__ __align__(16) unsigned int  TMP2[16 * 132]; // A pairs [n2][128d], pitch 132
    __shared__ float MS[64], LS[64];

    if (tid < Qn) {
        MS[tid] = Mrow[b * Qn + tid];
        LS[tid] = invL[b * Qn + tid];
    }

    f32x4 acc[4][2];
#pragma unroll
    for (int mi = 0; mi < 4; mi++)
#pragma unroll
        for (int ni = 0; ni < 2; ni++) acc[mi][ni] = 0.f;

    const int nv = nodeNum[b];
    const float* Abase = A + (size_t)b * Nn * Dn;

    for (int s = 0; s < NCHUNK / 32; s++) {
        const int n0 = chunk * NCHUNK + s * 32;
        __syncthreads();   // PS/TMP2 reuse fence (and MS/LS on first iter)

        // softmax: 64q x 32n = 512 float4-units of 4 n
#pragma unroll
        for (int t = 0; t < 2; t++) {
            int u = tid + t * 256;
            int q = u >> 3, ng = u & 7;
            size_t go = ((size_t)(b * Qn + q)) * Nn + n0 + ng * 4;
            float4 l4 = *(const float4*)(logits + go);
            float mq = MS[q], iq = LS[q];
            int nb = n0 + ng * 4;
            float4 p;
            p.x = (nb + 0 < nv) ? __expf(l4.x - mq) * iq : 0.f;
            p.y = (nb + 1 < nv) ? __expf(l4.y - mq) * iq : 0.f;
            p.z = (nb + 2 < nv) ? __expf(l4.z - mq) * iq : 0.f;
            p.w = (nb + 3 < nv) ? __expf(l4.w - mq) * iq : 0.f;
            *(float4*)(soft + go) = p;
            unsigned int* dst = (unsigned int*)(PS + q * 40 + ng * 4);
            dst[0] = cvt_pk_bf16(p.x, p.y);
            dst[1] = cvt_pk_bf16(p.z, p.w);
        }
        // stage A slab 32n x 128d as (n,n+1) bf16 pairs: 512 uint4-units
#pragma unroll
        for (int t = 0; t < 2; t++) {
            int u = tid + t * 256;
            int n2 = u >> 5, db = u & 31;
            const float* r0 = Abase + (size_t)(n0 + n2 * 2) * Dn + db * 4;
            float4 a0 = *(const float4*)r0;          // n even
            float4 a1 = *(const float4*)(r0 + Dn);   // n odd
            uint4 w;
            w.x = cvt_pk_bf16(a0.x, a1.x);
            w.y = cvt_pk_bf16(a0.y, a1.y);
            w.z = cvt_pk_bf16(a0.z, a1.z);
            w.w = cvt_pk_bf16(a0.w, a1.w);
            *(uint4*)(TMP2 + n2 * 132 + db * 4) = w;
        }
        __syncthreads();

        short8 pf[4];
#pragma unroll
        for (int mi = 0; mi < 4; mi++)
            pf[mi] = *(const short8*)(PS + (mi * 16 + cc) * 40 + qd * 8);
#pragma unroll
        for (int ni = 0; ni < 2; ni++) {
            int d = (wave * 2 + ni) * 16 + cc;
            pk8 bfr;
#pragma unroll
            for (int j = 0; j < 4; j++)
                bfr.u[j] = TMP2[(qd * 4 + j) * 132 + d];
#pragma unroll
            for (int mi = 0; mi < 4; mi++)
                acc[mi][ni] = __builtin_amdgcn_mfma_f32_16x16x32_bf16(
                    pf[mi], bfr.v, acc[mi][ni], 0, 0, 0);
        }
    }

    float* pout = partial8 + (size_t)(chunk & (NCOPY - 1)) * RES_ELEMS
                + (size_t)(b * Qn) * Dn;
#pragma unroll
    for (int mi = 0; mi < 4; mi++)
#pragma unroll
        for (int ni = 0; ni < 2; ni++)
#pragma unroll
            for (int r = 0; r < 4; r++) {
                int q = mi * 16 + qd * 4 + r;
                int d = (wave * 2 + ni) * 16 + cc;
                atomicAdd(&pout[q * Dn + d], acc[mi][ni][r]);
            }
}

// ---------------------------------------------------------------------------
// K4: res = sum over the 8 copies (4 MB read, ~1 us)
// ---------------------------------------------------------------------------
__global__ __launch_bounds__(256) void k_red8(
    const float* __restrict__ partial8, float* __restrict__ res)
{
    int g = blockIdx.x * 256 + threadIdx.x;
    float s = 0.f;
#pragma unroll
    for (int t = 0; t < NCOPY; t++)
        s += partial8[(size_t)t * RES_ELEMS + g];
    res[g] = s;
}

extern "C" void kernel_launch(void* const* d_in, const int* in_sizes, int n_in,
                              void* d_out, int out_size, void* d_ws, size_t ws_size,
                              hipStream_t stream) {
    const float* qv = (const float*)d_in[0];
    const float* A  = (const float*)d_in[1];
    const int*   nn = (const int*)d_in[2];

    float* out    = (float*)d_out;
    float* res    = out;
    float* soft   = out + SOFT_OFF;
    float* logits = out + LOG_OFF;

    float* ws      = (float*)d_ws;
    float* pmax    = ws;
    float* psum    = pmax + (size_t)Bn * Qn * NTILES;
    float* Mrow    = psum + (size_t)Bn * Qn * NTILES;
    float* invL    = Mrow + Bn * Qn;
    float* partial8 = invL + Bn * Qn;

    dim3 blk(256);
    // zero the 8 accumulation copies: NCOPY*RES_ELEMS floats / 4 / 256
    k_zero<<<(NCOPY * RES_ELEMS) / 1024, blk, 0, stream>>>(partial8);
    k_logits<<<dim3(NTILES, Bn), blk, 0, stream>>>(qv, A, nn, logits, pmax, psum);
    k_rows<<<Bn * Qn, 64, 0, stream>>>(pmax, psum, Mrow, invL);
    k_pv<<<dim3(NCHUNKS, Bn), blk, 0, stream>>>(A, nn, logits, Mrow, invL, soft, partial8);
    k_red8<<<RES_ELEMS / 256, blk, 0, stream>>>(partial8, res);
}